// Round 1
// baseline (330.323 us; speedup 1.0000x reference)
//
#include <hip/hip_runtime.h>
#include <hip/hip_fp16.h>

// GCN 2-layer forward on MI355X — R11: dinv folded into feature rows.
//  deg computed up-front (k_hist) -> GEMM1 writes h1' = (x@W1)*dinv (scaled
//  pre-round, fp32), agg1mm writes g' = h2*dinv likewise. Aggregation loops
//  lose the dinv gather stream and the per-edge weight FMA entirely:
//  out = dc * (sum h'[s] + h'[self]) + b.  esrc consumed as int4 (4 edges per
//  half per load): VMEM per 8 edges 12 -> 5.  Sentinel rows h1[N], g[N]
//  zeroed in k_scan (pad entries src=N contribute exact 0).
// d_in: [0]=x (N*128 f32), [1]=edge_index (2*E i32), [2]=W1 (128*64),
//       [3]=b1 (64), [4]=W2 (64*40), [5]=b2 (40)
// d_out: N*40 f32

#define FIN 128
#define H1  64
#define C2  40
#define GP  64            // padded row stride (halves) for g => 128 B lines
#define TILE 8192         // edges per scatter tile
#define THIST 2048        // edges per histogram tile
#define BCAP 6144         // padded bucket capacity (mean 4096+768 pad, sd 64)

// ---------- histogram: per-bucket counts (LDS) + per-node degree (global) ----------
__global__ __launch_bounds__(256) void k_hist(const int* __restrict__ col, int E,
                                              int* __restrict__ bucketCnt,
                                              int* __restrict__ deg, int NB) {
    __shared__ int lh[512];
    int t = threadIdx.x;
    for (int i = t; i < NB; i += 256) lh[i] = 0;
    __syncthreads();
    int base = blockIdx.x * THIST;
    int cnt = min(THIST, E - base);
    for (int i = t; i < cnt; i += 256) {
        int c = col[base + i];
        atomicAdd(&lh[c >> 8], 1);
        atomicAdd(&deg[c], 1);
    }
    __syncthreads();
    for (int b = t; b < NB; b += 256) if (lh[b]) atomicAdd(&bucketCnt[b], lh[b]);
}

// ---------- GEMM1, output scaled by dinv[node] before fp16 round ----------
__global__ __launch_bounds__(256) void k_gemm1(const float* __restrict__ x,
                                               const float* __restrict__ W1,
                                               const int* __restrict__ deg,
                                               __half* __restrict__ h1, int N) {
    __shared__ float smem[FIN * H1 + 64 * (FIN + 4)];   // 66560 B
    __shared__ float sdc[64];
    int t = threadIdx.x;
    float* Ws = smem;                     // [k][o] 32 KB
    float (*xs)[FIN + 4] = (float (*)[FIN + 4])(smem + FIN * H1);
    int node0 = blockIdx.x * 64;

    const float4* W4 = (const float4*)W1;
    float4* Ws4 = (float4*)Ws;
#pragma unroll
    for (int j = 0; j < 8; ++j) Ws4[t + j * 256] = W4[t + j * 256];

    const float4* x4 = (const float4*)x;
#pragma unroll
    for (int j = 0; j < 8; ++j) {
        int idx = t + j * 256;
        int r = idx >> 5, kq = idx & 31;
        int node = node0 + r; if (node >= N) node = N - 1;
        float4 v = x4[(size_t)node * 32 + kq];
        *(float4*)&xs[r][kq * 4] = v;
    }
    if (t < 64) {
        int node = node0 + t;
        sdc[t] = (node < N) ? rsqrtf((float)deg[node] + 1.0f) : 0.f;
    }
    __syncthreads();

    int og = t & 15, ng = t >> 4;
    int o0 = og * 4, n0 = ng * 4;
    float acc[4][4];
#pragma unroll
    for (int i = 0; i < 4; ++i)
#pragma unroll
        for (int j = 0; j < 4; ++j) acc[i][j] = 0.f;

#pragma unroll 8
    for (int k = 0; k < FIN; ++k) {
        float a0 = xs[n0 + 0][k], a1 = xs[n0 + 1][k];
        float a2 = xs[n0 + 2][k], a3 = xs[n0 + 3][k];
        float4 w = *(const float4*)&Ws[k * H1 + o0];
        acc[0][0] += a0 * w.x; acc[0][1] += a0 * w.y; acc[0][2] += a0 * w.z; acc[0][3] += a0 * w.w;
        acc[1][0] += a1 * w.x; acc[1][1] += a1 * w.y; acc[1][2] += a1 * w.z; acc[1][3] += a1 * w.w;
        acc[2][0] += a2 * w.x; acc[2][1] += a2 * w.y; acc[2][2] += a2 * w.z; acc[2][3] += a2 * w.w;
        acc[3][0] += a3 * w.x; acc[3][1] += a3 * w.y; acc[3][2] += a3 * w.z; acc[3][3] += a3 * w.w;
    }

#pragma unroll
    for (int i = 0; i < 4; ++i) {
        int node = node0 + n0 + i;
        if (node < N) {
            float dcv = sdc[n0 + i];
            union { __half h[4]; uint2 u; } pk;
            pk.h[0] = __float2half_rn(acc[i][0] * dcv);
            pk.h[1] = __float2half_rn(acc[i][1] * dcv);
            pk.h[2] = __float2half_rn(acc[i][2] * dcv);
            pk.h[3] = __float2half_rn(acc[i][3] * dcv);
            *(uint2*)&h1[(size_t)node * H1 + o0] = pk.u;
        }
    }
}

// ---------- single-block scan over NB buckets; zero sentinel rows ----------
__global__ __launch_bounds__(512) void k_scan(const int* __restrict__ bucketCnt,
                                              int* __restrict__ rawBase,
                                              int* __restrict__ padBase,
                                              int* __restrict__ gcursor,
                                              __half* __restrict__ h1,
                                              __half* __restrict__ g,
                                              int NB, int N) {
    __shared__ int sr[512], sp[512];
    int t = threadIdx.x;
    int c = (t < NB) ? bucketCnt[t] : 0;
    int p = (t < NB) ? (((c + 3) & ~3) + 1024) : 0;   // room for per-dest x4 pad
    sr[t] = c; sp[t] = p;
    __syncthreads();
    for (int off = 1; off < 512; off <<= 1) {
        int a = (t >= off) ? sr[t - off] : 0;
        int b = (t >= off) ? sp[t - off] : 0;
        __syncthreads();
        sr[t] += a; sp[t] += b;
        __syncthreads();
    }
    if (t <= NB) {
        rawBase[t] = sr[t] - ((t < NB) ? c : 0);
        padBase[t] = sp[t] - ((t < NB) ? p : 0);
        if (t < NB) gcursor[t] = sr[t] - c;
    }
    // sentinel rows: pad entries reference src == N and must contribute 0
    if (t < 32) ((unsigned*)(h1 + (size_t)N * H1))[t] = 0u;
    else if (t < 64) ((unsigned*)(g + (size_t)N * GP))[t - 32] = 0u;
}

// ---------- scatter into bucket-contiguous chunks (packed pairs) ----------
// packed: bits 0..23 = src row, bits 24..31 = dest low 8
__global__ __launch_bounds__(512) void k_scatter(const int* __restrict__ row,
                                                 const int* __restrict__ col,
                                                 int* __restrict__ gcursor,
                                                 int* __restrict__ pairs,
                                                 int E, int NB) {
    __shared__ int2 stage[TILE];         // 64 KB
    __shared__ int lcnt[512];
    __shared__ int lex[512];
    __shared__ int gbase[512];
    int t = threadIdx.x, tile = blockIdx.x;
    int base = tile * TILE;
    int cnt = min(TILE, E - base);

    lcnt[t] = 0;
    __syncthreads();
    for (int i = t; i < cnt; i += 512) atomicAdd(&lcnt[col[base + i] >> 8], 1);
    __syncthreads();

    int myc = lcnt[t];
    lex[t] = myc;
    __syncthreads();
    for (int off = 1; off < 512; off <<= 1) {
        int u = (t >= off) ? lex[t - off] : 0;
        __syncthreads();
        lex[t] += u;
        __syncthreads();
    }
    int ex = lex[t] - myc;
    __syncthreads();
    lex[t] = ex;
    lcnt[t] = ex;                         // local cursor
    if (t < NB && myc > 0) gbase[t] = atomicAdd(&gcursor[t], myc);
    __syncthreads();

    for (int i = t; i < cnt; i += 512) {
        int r = row[base + i], c = col[base + i];
        int lpos = atomicAdd(&lcnt[c >> 8], 1);
        stage[lpos] = make_int2(r, c);
    }
    __syncthreads();

    for (int i = t; i < cnt; i += 512) {
        int2 p = stage[i];
        int b = p.y >> 8;
        pairs[gbase[b] + (i - lex[b])] = p.x | ((p.y & 255) << 24);
    }
}

// ---------- per-bucket final sort by dest; padded esrc segments ----------
__global__ __launch_bounds__(512) void k_bucket(const int* __restrict__ pairs,
                                                const int* __restrict__ rawBase,
                                                const int* __restrict__ padBase,
                                                int* __restrict__ rowptr,
                                                int* __restrict__ esrc,
                                                int N, int NB) {
    __shared__ int dcnt[256];
    __shared__ int sr[256], sp[256];
    __shared__ int cur[256];
    __shared__ int outbuf[BCAP];         // 24 KB
    int t = threadIdx.x, b = blockIdx.x;
    int d0 = b << 8;
    int nd = min(256, N - d0);
    int bstart = rawBase[b];
    int cnt = rawBase[b + 1] - bstart;
    int pstart = padBase[b];

    if (t < 256) dcnt[t] = 0;
    __syncthreads();
    for (int i = t; i < cnt; i += 512) {
        unsigned p = (unsigned)pairs[bstart + i];
        atomicAdd(&dcnt[p >> 24], 1);
    }
    __syncthreads();

    int myc = 0, myp = 0;
    if (t < 256) {
        myc = dcnt[t];
        myp = (myc + 3) & ~3;
        sr[t] = myc; sp[t] = myp;
    }
    __syncthreads();
    for (int off = 1; off < 256; off <<= 1) {
        int a = 0, c2 = 0;
        if (t < 256 && t >= off) { a = sr[t - off]; c2 = sp[t - off]; }
        __syncthreads();
        if (t < 256) { sr[t] += a; sp[t] += c2; }
        __syncthreads();
    }
    if (t < 256) {
        int pex = sp[t] - myp;
        cur[t] = pex;
        if (t < nd) rowptr[d0 + t] = pstart + pex;
    }
    __syncthreads();
    int pcnt = sp[255];

    if (pcnt <= BCAP) {
        for (int i = t; i < cnt; i += 512) {
            unsigned p = (unsigned)pairs[bstart + i];
            int lpos = atomicAdd(&cur[p >> 24], 1);
            outbuf[lpos] = (int)(p & 0xFFFFFF);
        }
        __syncthreads();
        if (t < 256) {
            int pex = sp[t] - myp;
            for (int j = myc; j < myp; ++j) outbuf[pex + j] = N;   // sentinel pad
        }
        __syncthreads();
        for (int i = t; i < pcnt; i += 512) esrc[pstart + i] = outbuf[i];
    } else {
        for (int i = t; i < cnt; i += 512) {
            unsigned p = (unsigned)pairs[bstart + i];
            int lpos = atomicAdd(&cur[p >> 24], 1);
            esrc[pstart + lpos] = (int)(p & 0xFFFFFF);
        }
        __syncthreads();
        if (t < 256) {
            int pex = sp[t] - myp;
            for (int j = myc; j < myp; ++j) esrc[pstart + pex + j] = N;
        }
    }
}

// ---------- fused agg1 + bias + ReLU + GEMM2 per 64-node block ----------
// 512 threads = 8 waves. Aggregation: half 0 of a wave takes edges i..i+3,
// half 1 takes i+4..i+7 (one int4 esrc load each); each lane loads __half2
// (features 2f, 2f+1) of pre-scaled h1'. Pure adds; weight applied once per
// node (dc). Cross-half __shfl reduce. Then block GEMM2 from LDS, output
// rows scaled by dinv[node] pre-round (g' = h2*dinv).
__global__ __launch_bounds__(512) void k_agg1mm(const int* __restrict__ rowptr,
                                                const int* __restrict__ deg,
                                                const int* __restrict__ esrc,
                                                const __half* __restrict__ h1,
                                                const float* __restrict__ b1,
                                                const float* __restrict__ W2,
                                                __half* __restrict__ g, int N) {
    __shared__ float hs[64][H1 + 4];     // 17 KB: relu(agg1) rows
    __shared__ float Ws[H1 * C2];        // 10 KB, [k][c]
    __shared__ float sdc[64];
    int t = threadIdx.x;
    int node0 = blockIdx.x * 64;

    {   // stage W2: 640 float4
        const float4* W4 = (const float4*)W2;
        float4* Ws4 = (float4*)Ws;
        for (int i = t; i < 640; i += 512) Ws4[i] = W4[i];
    }

    int wv = t >> 6, lane = t & 63;
    int half = lane >> 5;                // edge-quad selector
    int f = lane & 31;                   // feature-pair index
    float2 b1v = *(const float2*)&b1[2 * f];
    const __half2* hp = (const __half2*)h1;

    // aggregation: 8 nodes per wave, sequential
    for (int j = 0; j < 8; ++j) {
        int r = wv * 8 + j;
        int node = node0 + r;
        if (node >= N) {
            if (lane < 32) { hs[r][2 * f] = 0.f; hs[r][2 * f + 1] = 0.f; }
            if (lane == 0) sdc[r] = 0.f;
            continue;
        }
        int start = rowptr[node], d = deg[node];
        int d4 = (d + 3) & ~3;
        float dc = rsqrtf((float)d + 1.0f);
        float ax = 0.f, ay = 0.f;
        int i = 0;
        for (; i + 8 <= d4; i += 8) {
            int4 s = *(const int4*)&esrc[start + i + half * 4];
            float2 v0 = __half22float2(hp[s.x * 32 + f]);
            float2 v1 = __half22float2(hp[s.y * 32 + f]);
            float2 v2 = __half22float2(hp[s.z * 32 + f]);
            float2 v3 = __half22float2(hp[s.w * 32 + f]);
            ax += (v0.x + v1.x) + (v2.x + v3.x);
            ay += (v0.y + v1.y) + (v2.y + v3.y);
        }
        if (i < d4 && half == 0) {       // 4-edge tail: half 0 only
            int4 s = *(const int4*)&esrc[start + i];
            float2 v0 = __half22float2(hp[s.x * 32 + f]);
            float2 v1 = __half22float2(hp[s.y * 32 + f]);
            float2 v2 = __half22float2(hp[s.z * 32 + f]);
            float2 v3 = __half22float2(hp[s.w * 32 + f]);
            ax += (v0.x + v1.x) + (v2.x + v3.x);
            ay += (v0.y + v1.y) + (v2.y + v3.y);
        }
        // cross-half reduce (both halves end with full sum)
        ax += __shfl(ax, lane ^ 32);
        ay += __shfl(ay, lane ^ 32);
        // self-loop (h1' already has one dinv factor) + bias + ReLU
        float2 sv = __half22float2(hp[node * 32 + f]);
        ax = fmaxf(fmaf(dc, ax + sv.x, b1v.x), 0.f);
        ay = fmaxf(fmaf(dc, ay + sv.y, b1v.y), 0.f);
        if (lane < 32) { hs[r][2 * f] = ax; hs[r][2 * f + 1] = ay; }
        if (lane == 0) sdc[r] = dc;
    }
    __syncthreads();

    // GEMM2 from LDS: 512 threads = 16 col-groups x 32 row-groups (2 rows each)
    int og = t & 15, ng = t >> 4;
    int o0 = og * 4, n0 = ng * 2;
    int o0c = (o0 <= 36) ? o0 : 36;
    float acc[2][4];
#pragma unroll
    for (int i = 0; i < 2; ++i)
#pragma unroll
        for (int j = 0; j < 4; ++j) acc[i][j] = 0.f;

#pragma unroll 8
    for (int k = 0; k < H1; ++k) {
        float a0 = hs[n0 + 0][k], a1 = hs[n0 + 1][k];
        float4 w = *(const float4*)&Ws[k * C2 + o0c];
        acc[0][0] += a0 * w.x; acc[0][1] += a0 * w.y; acc[0][2] += a0 * w.z; acc[0][3] += a0 * w.w;
        acc[1][0] += a1 * w.x; acc[1][1] += a1 * w.y; acc[1][2] += a1 * w.z; acc[1][3] += a1 * w.w;
    }

    if (o0 < C2) {
#pragma unroll
        for (int i = 0; i < 2; ++i) {
            int node = node0 + n0 + i;
            if (node < N) {
                float dcv = sdc[n0 + i];
                union { __half h[4]; uint2 u; } pk;
                pk.h[0] = __float2half_rn(acc[i][0] * dcv);
                pk.h[1] = __float2half_rn(acc[i][1] * dcv);
                pk.h[2] = __float2half_rn(acc[i][2] * dcv);
                pk.h[3] = __float2half_rn(acc[i][3] * dcv);
                *(uint2*)&g[(size_t)node * GP + o0] = pk.u;
            }
        }
    }
}

// ---------- agg2: wave per node, pre-scaled g' rows, int4 esrc ----------
__global__ __launch_bounds__(256) void k_agg2(const int* __restrict__ rowptr,
                                              const int* __restrict__ deg,
                                              const int* __restrict__ esrc,
                                              const __half* __restrict__ g,
                                              const float* __restrict__ b2,
                                              float* __restrict__ out, int N) {
    int w = (int)((blockIdx.x * blockDim.x + threadIdx.x) >> 6);
    int lane = threadIdx.x & 63;
    if (w >= N) return;
    int half = lane >> 5;
    int f = lane & 31;                   // feature-pair; active f<20
    bool act = f < 20;
    const __half2* gp = (const __half2*)g;

    int start = rowptr[w], d = deg[w];
    int d4 = (d + 3) & ~3;
    float dc = rsqrtf((float)d + 1.0f);
    float ax = 0.f, ay = 0.f;
    int i = 0;
    for (; i + 8 <= d4; i += 8) {
        int4 s = *(const int4*)&esrc[start + i + half * 4];
        float2 v0 = __half22float2(gp[s.x * 32 + f]);
        float2 v1 = __half22float2(gp[s.y * 32 + f]);
        float2 v2 = __half22float2(gp[s.z * 32 + f]);
        float2 v3 = __half22float2(gp[s.w * 32 + f]);
        ax += (v0.x + v1.x) + (v2.x + v3.x);
        ay += (v0.y + v1.y) + (v2.y + v3.y);
    }
    if (i < d4 && half == 0) {
        int4 s = *(const int4*)&esrc[start + i];
        float2 v0 = __half22float2(gp[s.x * 32 + f]);
        float2 v1 = __half22float2(gp[s.y * 32 + f]);
        float2 v2 = __half22float2(gp[s.z * 32 + f]);
        float2 v3 = __half22float2(gp[s.w * 32 + f]);
        ax += (v0.x + v1.x) + (v2.x + v3.x);
        ay += (v0.y + v1.y) + (v2.y + v3.y);
    }
    ax += __shfl(ax, lane ^ 32);
    ay += __shfl(ay, lane ^ 32);
    if (lane < 32 && act) {
        float2 b2v = *(const float2*)&b2[2 * f];
        float2 sv = __half22float2(gp[w * 32 + f]);
        float2 o;
        o.x = fmaf(dc, ax + sv.x, b2v.x);
        o.y = fmaf(dc, ay + sv.y, b2v.y);
        *(float2*)&out[(size_t)w * C2 + 2 * f] = o;
    }
}

extern "C" void kernel_launch(void* const* d_in, const int* in_sizes, int n_in,
                              void* d_out, int out_size, void* d_ws, size_t ws_size,
                              hipStream_t stream) {
    const float* x   = (const float*)d_in[0];
    const int*   ei  = (const int*)d_in[1];
    const float* W1  = (const float*)d_in[2];
    const float* b1  = (const float*)d_in[3];
    const float* W2  = (const float*)d_in[4];
    const float* b2  = (const float*)d_in[5];
    float* out = (float*)d_out;

    const int N = in_sizes[0] / FIN;       // 100000
    const int E = in_sizes[1] / 2;         // 1600000
    const int* row = ei;
    const int* col = ei + E;

    const int NB = (N + 255) >> 8;         // 391 buckets
    const int T  = (E + TILE - 1) / TILE;  // 196 scatter tiles
    const int HB = (E + THIST - 1) / THIST;// 782 histogram tiles
    const int EP = E + NB * 1024 + 1024;   // padded esrc capacity

    // workspace layout (bucketCnt+deg contiguous => one memset)
    char* ws = (char*)d_ws;
    size_t off = 0;
    int*    bucketCnt = (int*)(ws + off);    off += (size_t)NB * 4;
    int*    deg       = (int*)(ws + off);    off += (size_t)N * 4;
    int*    rawBase   = (int*)(ws + off);    off += (size_t)(NB + 1) * 4;
    int*    padBase   = (int*)(ws + off);    off += (size_t)(NB + 1) * 4;
    int*    gcursor   = (int*)(ws + off);    off += (size_t)NB * 4;
    int*    rowptr    = (int*)(ws + off);    off += (size_t)N * 4;
    int*    pairs     = (int*)(ws + off);    off += (size_t)E * 4;
    off = (off + 15) & ~(size_t)15;
    int*    esrc      = (int*)(ws + off);    off += (size_t)EP * 4;
    off = (off + 15) & ~(size_t)15;
    __half* h1        = (__half*)(ws + off); off += (size_t)(N + 1) * H1 * 2;
    off = (off + 15) & ~(size_t)15;
    __half* g         = (__half*)(ws + off); off += (size_t)(N + 1) * GP * 2;

    hipMemsetAsync(bucketCnt, 0, (size_t)(NB + N) * 4, stream);

    int gblocks = (N + 63) / 64;           // 1563

    // degree + bucket histogram (must precede GEMM1: h1 is pre-scaled)
    k_hist<<<HB, 256, 0, stream>>>(col, E, bucketCnt, deg, NB);

    // GEMM1, writes h1' = (x@W1)*dinv
    k_gemm1<<<gblocks, 256, 0, stream>>>(x, W1, deg, h1, N);

    // CSR build: scan (1 block) -> chunk-claim scatter -> bucket sort
    k_scan<<<1, 512, 0, stream>>>(bucketCnt, rawBase, padBase, gcursor, h1, g, NB, N);
    k_scatter<<<T, 512, 0, stream>>>(row, col, gcursor, pairs, E, NB);
    k_bucket<<<NB, 512, 0, stream>>>(pairs, rawBase, padBase, rowptr, esrc, N, NB);

    // layer 1 aggregation + bias + ReLU + GEMM2 (fused), writes g' = h2*dinv
    k_agg1mm<<<gblocks, 512, 0, stream>>>(rowptr, deg, esrc, h1, b1, W2, g, N);

    // layer 2 aggregation + bias
    k_agg2<<<((size_t)N * 64 + 255) / 256, 256, 0, stream>>>(rowptr, deg, esrc, g, b2, out, N);
}

// Round 2
// 260.380 us; speedup vs baseline: 1.2686x; 1.2686x over previous
//
#include <hip/hip_runtime.h>
#include <hip/hip_fp16.h>

// GCN 2-layer forward on MI355X — R12: dinv folded into feature rows, deg
// derived for free inside k_bucket (counting-sort byproduct) instead of the
// R11 global-atomic histogram (78 us -> ~4 us). Pipeline reordered so GEMM1
// runs after the CSR build (stream is serialized anyway):
//   hist(buckets) -> scan -> scatter -> bucket(deg) -> gemm1 -> agg1mm -> agg2
// GEMM1 writes h1' = (x@W1)*dinv pre-round; agg1mm writes g' = h2*dinv.
// Aggregation: out = dc * (sum h'[s] + h'[self]) + b; esrc consumed as int4
// (4 edges per wave-half per load). Sentinel rows h1[N], g[N] zeroed in
// k_scan (pad entries src=N contribute exact 0).
// d_in: [0]=x (N*128 f32), [1]=edge_index (2*E i32), [2]=W1 (128*64),
//       [3]=b1 (64), [4]=W2 (64*40), [5]=b2 (40)
// d_out: N*40 f32

#define FIN 128
#define H1  64
#define C2  40
#define GP  64            // padded row stride (halves) for g => 128 B lines
#define TILE 8192         // edges per hist/scatter tile
#define BCAP 6144         // padded bucket capacity (mean 4096+768 pad, sd 64)

// ---------- histogram: per-bucket counts only (LDS atomics) ----------
__global__ __launch_bounds__(256) void k_hist(const int* __restrict__ col, int E,
                                              int* __restrict__ bucketCnt, int NB) {
    __shared__ int lh[512];
    int t = threadIdx.x;
    for (int i = t; i < NB; i += 256) lh[i] = 0;
    __syncthreads();
    int base = blockIdx.x * TILE;
    int cnt = min(TILE, E - base);
    for (int i = t; i < cnt; i += 256) atomicAdd(&lh[col[base + i] >> 8], 1);
    __syncthreads();
    for (int b = t; b < NB; b += 256) if (lh[b]) atomicAdd(&bucketCnt[b], lh[b]);
}

// ---------- single-block scan over NB buckets; zero sentinel rows ----------
__global__ __launch_bounds__(512) void k_scan(const int* __restrict__ bucketCnt,
                                              int* __restrict__ rawBase,
                                              int* __restrict__ padBase,
                                              int* __restrict__ gcursor,
                                              __half* __restrict__ h1,
                                              __half* __restrict__ g,
                                              int NB, int N) {
    __shared__ int sr[512], sp[512];
    int t = threadIdx.x;
    int c = (t < NB) ? bucketCnt[t] : 0;
    int p = (t < NB) ? (((c + 3) & ~3) + 1024) : 0;   // room for per-dest x4 pad
    sr[t] = c; sp[t] = p;
    __syncthreads();
    for (int off = 1; off < 512; off <<= 1) {
        int a = (t >= off) ? sr[t - off] : 0;
        int b = (t >= off) ? sp[t - off] : 0;
        __syncthreads();
        sr[t] += a; sp[t] += b;
        __syncthreads();
    }
    if (t <= NB) {
        rawBase[t] = sr[t] - ((t < NB) ? c : 0);
        padBase[t] = sp[t] - ((t < NB) ? p : 0);
        if (t < NB) gcursor[t] = sr[t] - c;
    }
    // sentinel rows: pad entries reference src == N and must contribute 0
    if (t < 32) ((unsigned*)(h1 + (size_t)N * H1))[t] = 0u;
    else if (t < 64) ((unsigned*)(g + (size_t)N * GP))[t - 32] = 0u;
}

// ---------- scatter into bucket-contiguous chunks (packed pairs) ----------
// packed: bits 0..23 = src row, bits 24..31 = dest low 8
__global__ __launch_bounds__(512) void k_scatter(const int* __restrict__ row,
                                                 const int* __restrict__ col,
                                                 int* __restrict__ gcursor,
                                                 int* __restrict__ pairs,
                                                 int E, int NB) {
    __shared__ int2 stage[TILE];         // 64 KB
    __shared__ int lcnt[512];
    __shared__ int lex[512];
    __shared__ int gbase[512];
    int t = threadIdx.x, tile = blockIdx.x;
    int base = tile * TILE;
    int cnt = min(TILE, E - base);

    lcnt[t] = 0;
    __syncthreads();
    for (int i = t; i < cnt; i += 512) atomicAdd(&lcnt[col[base + i] >> 8], 1);
    __syncthreads();

    int myc = lcnt[t];
    lex[t] = myc;
    __syncthreads();
    for (int off = 1; off < 512; off <<= 1) {
        int u = (t >= off) ? lex[t - off] : 0;
        __syncthreads();
        lex[t] += u;
        __syncthreads();
    }
    int ex = lex[t] - myc;
    __syncthreads();
    lex[t] = ex;
    lcnt[t] = ex;                         // local cursor
    if (t < NB && myc > 0) gbase[t] = atomicAdd(&gcursor[t], myc);
    __syncthreads();

    for (int i = t; i < cnt; i += 512) {
        int r = row[base + i], c = col[base + i];
        int lpos = atomicAdd(&lcnt[c >> 8], 1);
        stage[lpos] = make_int2(r, c);
    }
    __syncthreads();

    for (int i = t; i < cnt; i += 512) {
        int2 p = stage[i];
        int b = p.y >> 8;
        pairs[gbase[b] + (i - lex[b])] = p.x | ((p.y & 255) << 24);
    }
}

// ---------- per-bucket final sort by dest; padded esrc segments; deg ----------
__global__ __launch_bounds__(512) void k_bucket(const int* __restrict__ pairs,
                                                const int* __restrict__ rawBase,
                                                const int* __restrict__ padBase,
                                                int* __restrict__ rowptr,
                                                int* __restrict__ deg,
                                                int* __restrict__ esrc,
                                                int N, int NB) {
    __shared__ int dcnt[256];
    __shared__ int sr[256], sp[256];
    __shared__ int cur[256];
    __shared__ int outbuf[BCAP];         // 24 KB
    int t = threadIdx.x, b = blockIdx.x;
    int d0 = b << 8;
    int nd = min(256, N - d0);
    int bstart = rawBase[b];
    int cnt = rawBase[b + 1] - bstart;
    int pstart = padBase[b];

    if (t < 256) dcnt[t] = 0;
    __syncthreads();
    for (int i = t; i < cnt; i += 512) {
        unsigned p = (unsigned)pairs[bstart + i];
        atomicAdd(&dcnt[p >> 24], 1);
    }
    __syncthreads();

    int myc = 0, myp = 0;
    if (t < 256) {
        myc = dcnt[t];
        myp = (myc + 3) & ~3;
        sr[t] = myc; sp[t] = myp;
    }
    __syncthreads();
    for (int off = 1; off < 256; off <<= 1) {
        int a = 0, c2 = 0;
        if (t < 256 && t >= off) { a = sr[t - off]; c2 = sp[t - off]; }
        __syncthreads();
        if (t < 256) { sr[t] += a; sp[t] += c2; }
        __syncthreads();
    }
    if (t < 256) {
        int pex = sp[t] - myp;
        cur[t] = pex;
        if (t < nd) {
            rowptr[d0 + t] = pstart + pex;
            deg[d0 + t] = myc;            // degree for free
        }
    }
    __syncthreads();
    int pcnt = sp[255];

    if (pcnt <= BCAP) {
        for (int i = t; i < cnt; i += 512) {
            unsigned p = (unsigned)pairs[bstart + i];
            int lpos = atomicAdd(&cur[p >> 24], 1);
            outbuf[lpos] = (int)(p & 0xFFFFFF);
        }
        __syncthreads();
        if (t < 256) {
            int pex = sp[t] - myp;
            for (int j = myc; j < myp; ++j) outbuf[pex + j] = N;   // sentinel pad
        }
        __syncthreads();
        for (int i = t; i < pcnt; i += 512) esrc[pstart + i] = outbuf[i];
    } else {
        for (int i = t; i < cnt; i += 512) {
            unsigned p = (unsigned)pairs[bstart + i];
            int lpos = atomicAdd(&cur[p >> 24], 1);
            esrc[pstart + lpos] = (int)(p & 0xFFFFFF);
        }
        __syncthreads();
        if (t < 256) {
            int pex = sp[t] - myp;
            for (int j = myc; j < myp; ++j) esrc[pstart + pex + j] = N;
        }
    }
}

// ---------- GEMM1, output scaled by dinv[node] before fp16 round ----------
__global__ __launch_bounds__(256) void k_gemm1(const float* __restrict__ x,
                                               const float* __restrict__ W1,
                                               const int* __restrict__ deg,
                                               __half* __restrict__ h1, int N) {
    __shared__ float smem[FIN * H1 + 64 * (FIN + 4)];   // 66560 B
    __shared__ float sdc[64];
    int t = threadIdx.x;
    float* Ws = smem;                     // [k][o] 32 KB
    float (*xs)[FIN + 4] = (float (*)[FIN + 4])(smem + FIN * H1);
    int node0 = blockIdx.x * 64;

    const float4* W4 = (const float4*)W1;
    float4* Ws4 = (float4*)Ws;
#pragma unroll
    for (int j = 0; j < 8; ++j) Ws4[t + j * 256] = W4[t + j * 256];

    const float4* x4 = (const float4*)x;
#pragma unroll
    for (int j = 0; j < 8; ++j) {
        int idx = t + j * 256;
        int r = idx >> 5, kq = idx & 31;
        int node = node0 + r; if (node >= N) node = N - 1;
        float4 v = x4[(size_t)node * 32 + kq];
        *(float4*)&xs[r][kq * 4] = v;
    }
    if (t < 64) {
        int node = node0 + t;
        sdc[t] = (node < N) ? rsqrtf((float)deg[node] + 1.0f) : 0.f;
    }
    __syncthreads();

    int og = t & 15, ng = t >> 4;
    int o0 = og * 4, n0 = ng * 4;
    float acc[4][4];
#pragma unroll
    for (int i = 0; i < 4; ++i)
#pragma unroll
        for (int j = 0; j < 4; ++j) acc[i][j] = 0.f;

#pragma unroll 8
    for (int k = 0; k < FIN; ++k) {
        float a0 = xs[n0 + 0][k], a1 = xs[n0 + 1][k];
        float a2 = xs[n0 + 2][k], a3 = xs[n0 + 3][k];
        float4 w = *(const float4*)&Ws[k * H1 + o0];
        acc[0][0] += a0 * w.x; acc[0][1] += a0 * w.y; acc[0][2] += a0 * w.z; acc[0][3] += a0 * w.w;
        acc[1][0] += a1 * w.x; acc[1][1] += a1 * w.y; acc[1][2] += a1 * w.z; acc[1][3] += a1 * w.w;
        acc[2][0] += a2 * w.x; acc[2][1] += a2 * w.y; acc[2][2] += a2 * w.z; acc[2][3] += a2 * w.w;
        acc[3][0] += a3 * w.x; acc[3][1] += a3 * w.y; acc[3][2] += a3 * w.z; acc[3][3] += a3 * w.w;
    }

#pragma unroll
    for (int i = 0; i < 4; ++i) {
        int node = node0 + n0 + i;
        if (node < N) {
            float dcv = sdc[n0 + i];
            union { __half h[4]; uint2 u; } pk;
            pk.h[0] = __float2half_rn(acc[i][0] * dcv);
            pk.h[1] = __float2half_rn(acc[i][1] * dcv);
            pk.h[2] = __float2half_rn(acc[i][2] * dcv);
            pk.h[3] = __float2half_rn(acc[i][3] * dcv);
            *(uint2*)&h1[(size_t)node * H1 + o0] = pk.u;
        }
    }
}

// ---------- fused agg1 + bias + ReLU + GEMM2 per 64-node block ----------
// 512 threads = 8 waves. Aggregation: half 0 of a wave takes edges i..i+3,
// half 1 takes i+4..i+7 (one int4 esrc load each); each lane loads __half2
// (features 2f, 2f+1) of pre-scaled h1'. Pure adds; weight applied once per
// node (dc). Cross-half __shfl reduce. Then block GEMM2 from LDS, output
// rows scaled by dinv[node] pre-round (g' = h2*dinv).
__global__ __launch_bounds__(512) void k_agg1mm(const int* __restrict__ rowptr,
                                                const int* __restrict__ deg,
                                                const int* __restrict__ esrc,
                                                const __half* __restrict__ h1,
                                                const float* __restrict__ b1,
                                                const float* __restrict__ W2,
                                                __half* __restrict__ g, int N) {
    __shared__ float hs[64][H1 + 4];     // 17 KB: relu(agg1) rows
    __shared__ float Ws[H1 * C2];        // 10 KB, [k][c]
    __shared__ float sdc[64];
    int t = threadIdx.x;
    int node0 = blockIdx.x * 64;

    {   // stage W2: 640 float4
        const float4* W4 = (const float4*)W2;
        float4* Ws4 = (float4*)Ws;
        for (int i = t; i < 640; i += 512) Ws4[i] = W4[i];
    }

    int wv = t >> 6, lane = t & 63;
    int half = lane >> 5;                // edge-quad selector
    int f = lane & 31;                   // feature-pair index
    float2 b1v = *(const float2*)&b1[2 * f];
    const __half2* hp = (const __half2*)h1;

    // aggregation: 8 nodes per wave, sequential
    for (int j = 0; j < 8; ++j) {
        int r = wv * 8 + j;
        int node = node0 + r;
        if (node >= N) {
            if (lane < 32) { hs[r][2 * f] = 0.f; hs[r][2 * f + 1] = 0.f; }
            if (lane == 0) sdc[r] = 0.f;
            continue;
        }
        int start = rowptr[node], d = deg[node];
        int d4 = (d + 3) & ~3;
        float dc = rsqrtf((float)d + 1.0f);
        float ax = 0.f, ay = 0.f;
        int i = 0;
        for (; i + 8 <= d4; i += 8) {
            int4 s = *(const int4*)&esrc[start + i + half * 4];
            float2 v0 = __half22float2(hp[s.x * 32 + f]);
            float2 v1 = __half22float2(hp[s.y * 32 + f]);
            float2 v2 = __half22float2(hp[s.z * 32 + f]);
            float2 v3 = __half22float2(hp[s.w * 32 + f]);
            ax += (v0.x + v1.x) + (v2.x + v3.x);
            ay += (v0.y + v1.y) + (v2.y + v3.y);
        }
        if (i < d4 && half == 0) {       // 4-edge tail: half 0 only
            int4 s = *(const int4*)&esrc[start + i];
            float2 v0 = __half22float2(hp[s.x * 32 + f]);
            float2 v1 = __half22float2(hp[s.y * 32 + f]);
            float2 v2 = __half22float2(hp[s.z * 32 + f]);
            float2 v3 = __half22float2(hp[s.w * 32 + f]);
            ax += (v0.x + v1.x) + (v2.x + v3.x);
            ay += (v0.y + v1.y) + (v2.y + v3.y);
        }
        // cross-half reduce (both halves end with full sum)
        ax += __shfl(ax, lane ^ 32);
        ay += __shfl(ay, lane ^ 32);
        // self-loop (h1' already has one dinv factor) + bias + ReLU
        float2 sv = __half22float2(hp[node * 32 + f]);
        ax = fmaxf(fmaf(dc, ax + sv.x, b1v.x), 0.f);
        ay = fmaxf(fmaf(dc, ay + sv.y, b1v.y), 0.f);
        if (lane < 32) { hs[r][2 * f] = ax; hs[r][2 * f + 1] = ay; }
        if (lane == 0) sdc[r] = dc;
    }
    __syncthreads();

    // GEMM2 from LDS: 512 threads = 16 col-groups x 32 row-groups (2 rows each)
    int og = t & 15, ng = t >> 4;
    int o0 = og * 4, n0 = ng * 2;
    int o0c = (o0 <= 36) ? o0 : 36;
    float acc[2][4];
#pragma unroll
    for (int i = 0; i < 2; ++i)
#pragma unroll
        for (int j = 0; j < 4; ++j) acc[i][j] = 0.f;

#pragma unroll 8
    for (int k = 0; k < H1; ++k) {
        float a0 = hs[n0 + 0][k], a1 = hs[n0 + 1][k];
        float4 w = *(const float4*)&Ws[k * C2 + o0c];
        acc[0][0] += a0 * w.x; acc[0][1] += a0 * w.y; acc[0][2] += a0 * w.z; acc[0][3] += a0 * w.w;
        acc[1][0] += a1 * w.x; acc[1][1] += a1 * w.y; acc[1][2] += a1 * w.z; acc[1][3] += a1 * w.w;
    }

    if (o0 < C2) {
#pragma unroll
        for (int i = 0; i < 2; ++i) {
            int node = node0 + n0 + i;
            if (node < N) {
                float dcv = sdc[n0 + i];
                union { __half h[4]; uint2 u; } pk;
                pk.h[0] = __float2half_rn(acc[i][0] * dcv);
                pk.h[1] = __float2half_rn(acc[i][1] * dcv);
                pk.h[2] = __float2half_rn(acc[i][2] * dcv);
                pk.h[3] = __float2half_rn(acc[i][3] * dcv);
                *(uint2*)&g[(size_t)node * GP + o0] = pk.u;
            }
        }
    }
}

// ---------- agg2: wave per node, pre-scaled g' rows, int4 esrc ----------
__global__ __launch_bounds__(256) void k_agg2(const int* __restrict__ rowptr,
                                              const int* __restrict__ deg,
                                              const int* __restrict__ esrc,
                                              const __half* __restrict__ g,
                                              const float* __restrict__ b2,
                                              float* __restrict__ out, int N) {
    int w = (int)((blockIdx.x * blockDim.x + threadIdx.x) >> 6);
    int lane = threadIdx.x & 63;
    if (w >= N) return;
    int half = lane >> 5;
    int f = lane & 31;                   // feature-pair; active f<20
    bool act = f < 20;
    const __half2* gp = (const __half2*)g;

    int start = rowptr[w], d = deg[w];
    int d4 = (d + 3) & ~3;
    float dc = rsqrtf((float)d + 1.0f);
    float ax = 0.f, ay = 0.f;
    int i = 0;
    for (; i + 8 <= d4; i += 8) {
        int4 s = *(const int4*)&esrc[start + i + half * 4];
        float2 v0 = __half22float2(gp[s.x * 32 + f]);
        float2 v1 = __half22float2(gp[s.y * 32 + f]);
        float2 v2 = __half22float2(gp[s.z * 32 + f]);
        float2 v3 = __half22float2(gp[s.w * 32 + f]);
        ax += (v0.x + v1.x) + (v2.x + v3.x);
        ay += (v0.y + v1.y) + (v2.y + v3.y);
    }
    if (i < d4 && half == 0) {
        int4 s = *(const int4*)&esrc[start + i];
        float2 v0 = __half22float2(gp[s.x * 32 + f]);
        float2 v1 = __half22float2(gp[s.y * 32 + f]);
        float2 v2 = __half22float2(gp[s.z * 32 + f]);
        float2 v3 = __half22float2(gp[s.w * 32 + f]);
        ax += (v0.x + v1.x) + (v2.x + v3.x);
        ay += (v0.y + v1.y) + (v2.y + v3.y);
    }
    ax += __shfl(ax, lane ^ 32);
    ay += __shfl(ay, lane ^ 32);
    if (lane < 32 && act) {
        float2 b2v = *(const float2*)&b2[2 * f];
        float2 sv = __half22float2(gp[w * 32 + f]);
        float2 o;
        o.x = fmaf(dc, ax + sv.x, b2v.x);
        o.y = fmaf(dc, ay + sv.y, b2v.y);
        *(float2*)&out[(size_t)w * C2 + 2 * f] = o;
    }
}

extern "C" void kernel_launch(void* const* d_in, const int* in_sizes, int n_in,
                              void* d_out, int out_size, void* d_ws, size_t ws_size,
                              hipStream_t stream) {
    const float* x   = (const float*)d_in[0];
    const int*   ei  = (const int*)d_in[1];
    const float* W1  = (const float*)d_in[2];
    const float* b1  = (const float*)d_in[3];
    const float* W2  = (const float*)d_in[4];
    const float* b2  = (const float*)d_in[5];
    float* out = (float*)d_out;

    const int N = in_sizes[0] / FIN;       // 100000
    const int E = in_sizes[1] / 2;         // 1600000
    const int* row = ei;
    const int* col = ei + E;

    const int NB = (N + 255) >> 8;         // 391 buckets
    const int T  = (E + TILE - 1) / TILE;  // 196 tiles
    const int EP = E + NB * 1024 + 1024;   // padded esrc capacity

    // workspace layout
    char* ws = (char*)d_ws;
    size_t off = 0;
    int*    bucketCnt = (int*)(ws + off);    off += (size_t)NB * 4;
    int*    rawBase   = (int*)(ws + off);    off += (size_t)(NB + 1) * 4;
    int*    padBase   = (int*)(ws + off);    off += (size_t)(NB + 1) * 4;
    int*    gcursor   = (int*)(ws + off);    off += (size_t)NB * 4;
    int*    deg       = (int*)(ws + off);    off += (size_t)N * 4;
    int*    rowptr    = (int*)(ws + off);    off += (size_t)N * 4;
    int*    pairs     = (int*)(ws + off);    off += (size_t)E * 4;
    off = (off + 15) & ~(size_t)15;
    int*    esrc      = (int*)(ws + off);    off += (size_t)EP * 4;
    off = (off + 15) & ~(size_t)15;
    __half* h1        = (__half*)(ws + off); off += (size_t)(N + 1) * H1 * 2;
    off = (off + 15) & ~(size_t)15;
    __half* g         = (__half*)(ws + off); off += (size_t)(N + 1) * GP * 2;

    hipMemsetAsync(bucketCnt, 0, (size_t)NB * 4, stream);

    int gblocks = (N + 63) / 64;           // 1563

    // CSR build: bucket histogram -> scan -> chunk-claim scatter -> bucket
    // sort (also emits deg for free from the per-dest counts)
    k_hist<<<T, 256, 0, stream>>>(col, E, bucketCnt, NB);
    k_scan<<<1, 512, 0, stream>>>(bucketCnt, rawBase, padBase, gcursor, h1, g, NB, N);
    k_scatter<<<T, 512, 0, stream>>>(row, col, gcursor, pairs, E, NB);
    k_bucket<<<NB, 512, 0, stream>>>(pairs, rawBase, padBase, rowptr, deg, esrc, N, NB);

    // GEMM1, writes h1' = (x@W1)*dinv  (needs deg => after k_bucket)
    k_gemm1<<<gblocks, 256, 0, stream>>>(x, W1, deg, h1, N);

    // layer 1 aggregation + bias + ReLU + GEMM2 (fused), writes g' = h2*dinv
    k_agg1mm<<<gblocks, 512, 0, stream>>>(rowptr, deg, esrc, h1, b1, W2, g, N);

    // layer 2 aggregation + bias
    k_agg2<<<((size_t)N * 64 + 255) / 256, 256, 0, stream>>>(rowptr, deg, esrc, g, b2, out, N);
}